// Round 1
// baseline (1048.412 us; speedup 1.0000x reference)
//
#include <hip/hip_runtime.h>
#include <hip/hip_bf16.h>

#define B_    2
#define S_    1024
#define HID_  4096
#define H_    32
#define HKV_  8
#define HD_   128

typedef __attribute__((ext_vector_type(8))) short   bf16x8_t;
typedef __attribute__((ext_vector_type(4))) float   f32x4_t;

__device__ __forceinline__ unsigned short f2bf(float f) {
    union { float f; unsigned u; } v; v.f = f;
    unsigned r = v.u + 0x7fffu + ((v.u >> 16) & 1u);
    return (unsigned short)(r >> 16);
}
__device__ __forceinline__ float bf2f(unsigned short u) {
    union { unsigned u; float f; } v; v.u = ((unsigned)u) << 16;
    return v.f;
}

// ---------------- convert fp32 -> bf16 (vectorized) ----------------
__global__ __launch_bounds__(256) void cvt_f32_bf16(const float* __restrict__ in,
                                                    unsigned short* __restrict__ out,
                                                    int n4) {
    int i = blockIdx.x * 256 + threadIdx.x;
    if (i >= n4) return;
    float4 v = reinterpret_cast<const float4*>(in)[i];
    uint2 p;
    p.x = (unsigned)f2bf(v.x) | ((unsigned)f2bf(v.y) << 16);
    p.y = (unsigned)f2bf(v.z) | ((unsigned)f2bf(v.w) << 16);
    reinterpret_cast<uint2*>(out)[i] = p;
}

// ---------------- GEMM: C[M,N] = A(bf16)[M,K] @ B(f32)[K,N] ----------------
// 128x128 tile, BK=32, 4 waves (2x2), per-wave 64x64 via 4x4 16x16x32 MFMA.
template<bool OUT_BF16>
__global__ __launch_bounds__(256) void gemm_bf16a_f32b(
    const unsigned short* __restrict__ A,
    const float* __restrict__ Bm,
    void* __restrict__ Cm,
    int M, int N, int K)
{
    __shared__ unsigned short As[128][40];   // [m][k] pad->80B stride (16B aligned)
    __shared__ unsigned short Bs[128][40];   // transposed [n][k]
    const int tid  = threadIdx.x;
    const int lane = tid & 63;
    const int w    = tid >> 6;
    const int wm   = w >> 1, wn = w & 1;
    const int r    = lane & 15, g = lane >> 4;
    const int m0   = blockIdx.y * 128, n0 = blockIdx.x * 128;

    const f32x4_t zero = {0.f, 0.f, 0.f, 0.f};
    f32x4_t acc[4][4];
#pragma unroll
    for (int i = 0; i < 4; ++i)
#pragma unroll
        for (int j = 0; j < 4; ++j) acc[i][j] = zero;

    for (int k0 = 0; k0 < K; k0 += 32) {
        __syncthreads();
        // stage A tile (bf16, 128x32): 512 chunks of 8 elems, 2 per thread
#pragma unroll
        for (int p = 0; p < 2; ++p) {
            int c = tid + p * 256;
            int row = c >> 2, col = (c & 3) << 3;
            bf16x8_t v = *reinterpret_cast<const bf16x8_t*>(&A[(size_t)(m0 + row) * K + k0 + col]);
            *reinterpret_cast<bf16x8_t*>(&As[row][col]) = v;
        }
        // stage B tile (f32 32x128) -> transposed bf16 Bs[n][k]
#pragma unroll
        for (int p = 0; p < 4; ++p) {
            int q  = tid + p * 256;
            int c  = q & 127;       // n within tile
            int kb = q >> 7;        // 0..7 -> k block of 4
            const float* bp = &Bm[(size_t)(k0 + kb * 4) * N + n0 + c];
            unsigned short t0 = f2bf(bp[0]);
            unsigned short t1 = f2bf(bp[(size_t)N]);
            unsigned short t2 = f2bf(bp[2 * (size_t)N]);
            unsigned short t3 = f2bf(bp[3 * (size_t)N]);
            uint2 pk;
            pk.x = (unsigned)t0 | ((unsigned)t1 << 16);
            pk.y = (unsigned)t2 | ((unsigned)t3 << 16);
            *reinterpret_cast<uint2*>(&Bs[c][kb << 2]) = pk;
        }
        __syncthreads();

        bf16x8_t af[4], bfr[4];
#pragma unroll
        for (int m = 0; m < 4; ++m)
            af[m] = *reinterpret_cast<const bf16x8_t*>(&As[wm * 64 + m * 16 + r][g * 8]);
#pragma unroll
        for (int n = 0; n < 4; ++n)
            bfr[n] = *reinterpret_cast<const bf16x8_t*>(&Bs[wn * 64 + n * 16 + r][g * 8]);
#pragma unroll
        for (int m = 0; m < 4; ++m)
#pragma unroll
            for (int n = 0; n < 4; ++n)
                acc[m][n] = __builtin_amdgcn_mfma_f32_16x16x32_bf16(af[m], bfr[n], acc[m][n], 0, 0, 0);
    }

    // epilogue: D row=(lane>>4)*4+j, col=lane&15 (m89-verified layout)
#pragma unroll
    for (int m = 0; m < 4; ++m)
#pragma unroll
        for (int n = 0; n < 4; ++n)
#pragma unroll
            for (int j = 0; j < 4; ++j) {
                int row = m0 + wm * 64 + m * 16 + g * 4 + j;
                int col = n0 + wn * 64 + n * 16 + r;
                if constexpr (OUT_BF16)
                    reinterpret_cast<unsigned short*>(Cm)[(size_t)row * N + col] = f2bf(acc[m][n][j]);
                else
                    reinterpret_cast<float*>(Cm)[(size_t)row * N + col] = acc[m][n][j];
            }
}

// ---------------- rope table: tab[tok][0:64]=cos, [64:128]=sin ----------------
__global__ __launch_bounds__(256) void rope_table_kernel(const int* __restrict__ start_pos,
                                                         float* __restrict__ tab) {
    int i = blockIdx.x * 256 + threadIdx.x;   // B*S*64
    int d = i & 63;
    int tok = i >> 6;
    int s = tok & (S_ - 1);
    int b = tok >> 10;
    float pos = (float)(start_pos[b] + s);
    // inv_freq = 10000^(-d/64)
    float freq = __expf(-(float)d * (9.210340371976184f / 64.f));
    float ang = pos * freq;
    tab[tok * 128 + d]      = cosf(ang);
    tab[tok * 128 + 64 + d] = sinf(ang);
}

// ---------------- in-place NeoX rotary on bf16 [tok][Hn][128] ----------------
template<int LOGH>
__global__ __launch_bounds__(256) void rope_apply_kernel(unsigned short* __restrict__ t,
                                                         const float* __restrict__ tab) {
    int i = blockIdx.x * 256 + threadIdx.x;   // B*S*Hn*64
    int d = i & 63;
    int h = (i >> 6) & ((1 << LOGH) - 1);
    int tok = i >> (6 + LOGH);
    size_t base = ((size_t)tok << (7 + LOGH)) + ((size_t)h << 7);
    float c  = tab[tok * 128 + d];
    float sn = tab[tok * 128 + 64 + d];
    float a = bf2f(t[base + d]);
    float b = bf2f(t[base + 64 + d]);
    t[base + d]      = f2bf(a * c - b * sn);
    t[base + 64 + d] = f2bf(b * c + a * sn);
}

// ---------------- flash attention: 1 wave per (b, h, 16-row q tile) ----------------
__global__ __launch_bounds__(64) void attn_fwd(
    const unsigned short* __restrict__ Qb,   // [B*S, H*HD]
    const unsigned short* __restrict__ Kb,   // [B*S, HKV*HD]
    const unsigned short* __restrict__ Vb,   // [B*S, HKV*HD]
    unsigned short* __restrict__ Ob)         // [B*S, H*HD]
{
    const int qt = blockIdx.x, h = blockIdx.y, b = blockIdx.z;
    const int kvh = h >> 2;                   // g = H/HKV = 4
    const int lane = threadIdx.x;
    const int r = lane & 15, g = lane >> 4;
    __shared__ unsigned short P_lds[16][40];      // [qrow][kv] padded, 80B stride
    __shared__ unsigned short V_lds[32][128];     // [kv][hd] linear

    const int qrow0 = qt * 16;
    const unsigned short* Qp = Qb + ((size_t)(b * S_) + qrow0) * (H_ * HD_) + h * HD_;
    bf16x8_t qf[4];
#pragma unroll
    for (int kk = 0; kk < 4; ++kk)
        qf[kk] = *reinterpret_cast<const bf16x8_t*>(&Qp[(size_t)r * (H_ * HD_) + kk * 32 + g * 8]);

    const f32x4_t zero = {0.f, 0.f, 0.f, 0.f};
    f32x4_t o[8];
#pragma unroll
    for (int n = 0; n < 8; ++n) o[n] = zero;
    float m_[4], s_[4];
#pragma unroll
    for (int j = 0; j < 4; ++j) { m_[j] = -1e30f; s_[j] = 0.f; }

    const float scale = 0.08838834764831845f;   // 1/sqrt(128)
    const unsigned short* Kp = Kb + (size_t)b * S_ * (HKV_ * HD_) + kvh * HD_;
    const unsigned short* Vp = Vb + (size_t)b * S_ * (HKV_ * HD_) + kvh * HD_;
    const int ntiles = (qrow0 + 16 + 31) >> 5;

    for (int t = 0; t < ntiles; ++t) {
        const int k0 = t << 5;
        // ---- QK^T for 32 kv cols (two 16-col halves) ----
        f32x4_t sc0 = zero, sc1 = zero;
#pragma unroll
        for (int kk = 0; kk < 4; ++kk) {
            bf16x8_t kf0 = *reinterpret_cast<const bf16x8_t*>(
                &Kp[(size_t)(k0 + r) * (HKV_ * HD_) + kk * 32 + g * 8]);
            bf16x8_t kf1 = *reinterpret_cast<const bf16x8_t*>(
                &Kp[(size_t)(k0 + 16 + r) * (HKV_ * HD_) + kk * 32 + g * 8]);
            sc0 = __builtin_amdgcn_mfma_f32_16x16x32_bf16(qf[kk], kf0, sc0, 0, 0, 0);
            sc1 = __builtin_amdgcn_mfma_f32_16x16x32_bf16(qf[kk], kf1, sc1, 0, 0, 0);
        }
        // ---- stage V tile [32][128] into LDS (coalesced 16B) ----
#pragma unroll
        for (int p = 0; p < 8; ++p) {
            int i = lane + (p << 6);
            int vr = i >> 4, vc = (i & 15) << 3;
            *reinterpret_cast<bf16x8_t*>(&V_lds[vr][vc]) =
                *reinterpret_cast<const bf16x8_t*>(&Vp[(size_t)(k0 + vr) * (HKV_ * HD_) + vc]);
        }
        // ---- online softmax (rows g*4+j live in this 16-lane group) ----
        float p0[4], p1[4], al[4];
#pragma unroll
        for (int j = 0; j < 4; ++j) {
            int row = qrow0 + g * 4 + j;
            float v0 = sc0[j] * scale + ((k0 + r)      > row ? -1e9f : 0.f);
            float v1 = sc1[j] * scale + ((k0 + 16 + r) > row ? -1e9f : 0.f);
            float mx = fmaxf(v0, v1);
#pragma unroll
            for (int off = 1; off < 16; off <<= 1)
                mx = fmaxf(mx, __shfl_xor(mx, off));
            float mn = fmaxf(m_[j], mx);
            al[j] = __expf(m_[j] - mn);
            p0[j] = __expf(v0 - mn);
            p1[j] = __expf(v1 - mn);
            float rs = p0[j] + p1[j];
#pragma unroll
            for (int off = 1; off < 16; off <<= 1)
                rs += __shfl_xor(rs, off);
            s_[j] = s_[j] * al[j] + rs;
            m_[j] = mn;
        }
#pragma unroll
        for (int n = 0; n < 8; ++n)
#pragma unroll
            for (int j = 0; j < 4; ++j)
                o[n][j] *= al[j];
        // ---- P (16x32) -> LDS for A-operand re-layout ----
#pragma unroll
        for (int j = 0; j < 4; ++j) {
            P_lds[g * 4 + j][r]      = f2bf(p0[j]);
            P_lds[g * 4 + j][16 + r] = f2bf(p1[j]);
        }
        __syncthreads();
        bf16x8_t pa = *reinterpret_cast<const bf16x8_t*>(&P_lds[r][g * 8]);
        // ---- PV: O += P @ V (K=32) ----
#pragma unroll
        for (int n = 0; n < 8; ++n) {
            union { bf16x8_t v; unsigned short u[8]; } vb;
#pragma unroll
            for (int j = 0; j < 8; ++j)
                vb.u[j] = V_lds[g * 8 + j][n * 16 + r];
            o[n] = __builtin_amdgcn_mfma_f32_16x16x32_bf16(pa, vb.v, o[n], 0, 0, 0);
        }
        __syncthreads();
    }
    // ---- epilogue: normalize + store bf16 ----
    unsigned short* Op = Ob + ((size_t)(b * S_) + qrow0) * (H_ * HD_) + h * HD_;
#pragma unroll
    for (int n = 0; n < 8; ++n)
#pragma unroll
        for (int j = 0; j < 4; ++j) {
            float val = o[n][j] / s_[j];
            Op[(size_t)(g * 4 + j) * (H_ * HD_) + n * 16 + r] = f2bf(val);
        }
}

// ---------------- launcher ----------------
extern "C" void kernel_launch(void* const* d_in, const int* in_sizes, int n_in,
                              void* d_out, int out_size, void* d_ws, size_t ws_size,
                              hipStream_t stream)
{
    const float* x  = (const float*)d_in[0];
    const float* wq = (const float*)d_in[2];
    const float* wk = (const float*)d_in[3];
    const float* wv = (const float*)d_in[4];
    const float* wo = (const float*)d_in[5];
    const int* start_pos = (const int*)d_in[10];

    char* ws = (char*)d_ws;
    unsigned short* xb = (unsigned short*)(ws);                        // 16 MB  x bf16
    unsigned short* qb = (unsigned short*)(ws + 16777216);             // 16 MB  Q
    unsigned short* kb = (unsigned short*)(ws + 33554432);             // 4 MB   K
    unsigned short* vb = (unsigned short*)(ws + 37748736);             // 4 MB   V
    unsigned short* ab = (unsigned short*)(ws + 41943040);             // 16 MB  attn out
    float*          tb = (float*)(ws + 58720256);                      // 1 MB   rope table

    // 1) x -> bf16
    cvt_f32_bf16<<<8192, 256, 0, stream>>>(x, xb, (B_ * S_ * HID_) / 4);

    // 2) QKV projections (bf16 MFMA, fp32 weights converted in staging)
    gemm_bf16a_f32b<true><<<dim3(32, 16), 256, 0, stream>>>(xb, wq, qb, B_ * S_, H_ * HD_, HID_);
    gemm_bf16a_f32b<true><<<dim3(8, 16),  256, 0, stream>>>(xb, wk, kb, B_ * S_, HKV_ * HD_, HID_);
    gemm_bf16a_f32b<true><<<dim3(8, 16),  256, 0, stream>>>(xb, wv, vb, B_ * S_, HKV_ * HD_, HID_);

    // 3) rotary
    rope_table_kernel<<<512, 256, 0, stream>>>(start_pos, tb);
    rope_apply_kernel<5><<<16384, 256, 0, stream>>>(qb, tb);   // Q: 32 heads
    rope_apply_kernel<3><<<4096, 256, 0, stream>>>(kb, tb);    // K: 8 heads

    // 4) causal GQA flash attention
    attn_fwd<<<dim3(S_ / 16, H_, B_), 64, 0, stream>>>(qb, kb, vb, ab);

    // 5) output projection -> fp32 d_out
    gemm_bf16a_f32b<false><<<dim3(32, 16), 256, 0, stream>>>(ab, wo, (float*)d_out, B_ * S_, HID_, HID_);
}

// Round 2
// 807.779 us; speedup vs baseline: 1.2979x; 1.2979x over previous
//
#include <hip/hip_runtime.h>
#include <hip/hip_bf16.h>

#define B_    2
#define S_    1024
#define HID_  4096
#define H_    32
#define HKV_  8
#define HD_   128

typedef __attribute__((ext_vector_type(8))) short   bf16x8_t;
typedef __attribute__((ext_vector_type(4))) float   f32x4_t;

__device__ __forceinline__ unsigned short f2bf(float f) {
    union { float f; unsigned u; } v; v.f = f;
    unsigned r = v.u + 0x7fffu + ((v.u >> 16) & 1u);
    return (unsigned short)(r >> 16);
}
__device__ __forceinline__ float bf2f(unsigned short u) {
    union { unsigned u; float f; } v; v.u = ((unsigned)u) << 16;
    return v.f;
}

__device__ __forceinline__ void gload_lds16(const void* g, void* l) {
    __builtin_amdgcn_global_load_lds(
        (const __attribute__((address_space(1))) unsigned int*)g,
        (__attribute__((address_space(3))) unsigned int*)l, 16, 0, 0);
}

// ---------------- convert fp32 -> bf16 (vectorized) ----------------
__global__ __launch_bounds__(256) void cvt_f32_bf16(const float* __restrict__ in,
                                                    unsigned short* __restrict__ out,
                                                    int n4) {
    int i = blockIdx.x * 256 + threadIdx.x;
    if (i >= n4) return;
    float4 v = reinterpret_cast<const float4*>(in)[i];
    uint2 p;
    p.x = (unsigned)f2bf(v.x) | ((unsigned)f2bf(v.y) << 16);
    p.y = (unsigned)f2bf(v.z) | ((unsigned)f2bf(v.w) << 16);
    reinterpret_cast<uint2*>(out)[i] = p;
}

// ---------------- transpose+convert: W fp32 [K][ldW] (cols pre-offset) -> Wt bf16 [n][K] ----------------
// grid: (ncols/32, K/32), 256 threads. 32x32 tiles via LDS.
__global__ __launch_bounds__(256) void tcvt(const float* __restrict__ W,
                                            unsigned short* __restrict__ Wt,
                                            int ldW, int Kdim) {
    __shared__ unsigned short L[32][36];
    const int t = threadIdx.x;
    const int kb = blockIdx.y, nb = blockIdx.x;
    {
        int kr = t >> 3, nc = (t & 7) * 4;
        float4 v = *reinterpret_cast<const float4*>(&W[(size_t)(kb * 32 + kr) * ldW + nb * 32 + nc]);
        L[nc + 0][kr] = f2bf(v.x);
        L[nc + 1][kr] = f2bf(v.y);
        L[nc + 2][kr] = f2bf(v.z);
        L[nc + 3][kr] = f2bf(v.w);
    }
    __syncthreads();
    {
        int nr = t >> 3, kc = (t & 7) * 4;
        uint2 o;
        o.x = (unsigned)L[nr][kc + 0] | ((unsigned)L[nr][kc + 1] << 16);
        o.y = (unsigned)L[nr][kc + 2] | ((unsigned)L[nr][kc + 3] << 16);
        *reinterpret_cast<uint2*>(&Wt[(size_t)(nb * 32 + nr) * Kdim + kb * 32 + kc]) = o;
    }
}

// ---------------- GEMM (m97 structure): C = A[M][K] @ Bt[N][K]^T ----------------
// 128x128 tile, BK=32, 4 waves (2x2), global_load_lds width-16 staging, linear LDS.
template<bool OUT_BF16>
__global__ __launch_bounds__(256) void gemm_tt(
    const unsigned short* __restrict__ A,    // [M][K]
    const unsigned short* __restrict__ Bt,   // [N][K] (rows local to this call)
    void* __restrict__ Cm,                   // pre-offset by caller; ldc full row
    int ldc, int K)
{
    __shared__ unsigned short As[128 * 32];
    __shared__ unsigned short Bs[128 * 32];
    const int tid  = threadIdx.x;
    const int lane = tid & 63;
    const int w    = tid >> 6;
    const int wm   = w >> 1, wn = w & 1;
    const int r    = lane & 15, g = lane >> 4;
    const int m0   = blockIdx.y * 128, n0 = blockIdx.x * 128;

    // staging chunk geometry: chunk c covers row c>>2, cols [(c&3)*8, +8)
    const int c0 = w * 128 + lane;        // issue p=0
    const int c1 = c0 + 64;               // issue p=1
    const int r0 = c0 >> 2, col0 = (c0 & 3) << 3;
    const int r1 = c1 >> 2, col1 = (c1 & 3) << 3;

    const f32x4_t zero = {0.f, 0.f, 0.f, 0.f};
    f32x4_t acc[4][4];
#pragma unroll
    for (int i = 0; i < 4; ++i)
#pragma unroll
        for (int j = 0; j < 4; ++j) acc[i][j] = zero;

    for (int k0 = 0; k0 < K; k0 += 32) {
        __syncthreads();
        gload_lds16(&A [(size_t)(m0 + r0) * K + k0 + col0], As + (size_t)(w * 2 + 0) * 512);
        gload_lds16(&A [(size_t)(m0 + r1) * K + k0 + col1], As + (size_t)(w * 2 + 1) * 512);
        gload_lds16(&Bt[(size_t)(n0 + r0) * K + k0 + col0], Bs + (size_t)(w * 2 + 0) * 512);
        gload_lds16(&Bt[(size_t)(n0 + r1) * K + k0 + col1], Bs + (size_t)(w * 2 + 1) * 512);
        __syncthreads();

        bf16x8_t af[4], bfr[4];
#pragma unroll
        for (int m = 0; m < 4; ++m)
            af[m] = *reinterpret_cast<const bf16x8_t*>(&As[(wm * 64 + m * 16 + r) * 32 + g * 8]);
#pragma unroll
        for (int n = 0; n < 4; ++n)
            bfr[n] = *reinterpret_cast<const bf16x8_t*>(&Bs[(wn * 64 + n * 16 + r) * 32 + g * 8]);
#pragma unroll
        for (int m = 0; m < 4; ++m)
#pragma unroll
            for (int n = 0; n < 4; ++n)
                acc[m][n] = __builtin_amdgcn_mfma_f32_16x16x32_bf16(af[m], bfr[n], acc[m][n], 0, 0, 0);
    }

#pragma unroll
    for (int m = 0; m < 4; ++m)
#pragma unroll
        for (int n = 0; n < 4; ++n)
#pragma unroll
            for (int j = 0; j < 4; ++j) {
                int row = m0 + wm * 64 + m * 16 + g * 4 + j;
                int col = n0 + wn * 64 + n * 16 + r;
                if constexpr (OUT_BF16)
                    reinterpret_cast<unsigned short*>(Cm)[(size_t)row * ldc + col] = f2bf(acc[m][n][j]);
                else
                    reinterpret_cast<float*>(Cm)[(size_t)row * ldc + col] = acc[m][n][j];
            }
}

// ---------------- rope table: tab[tok][0:64]=cos, [64:128]=sin ----------------
__global__ __launch_bounds__(256) void rope_table_kernel(const int* __restrict__ start_pos,
                                                         float* __restrict__ tab) {
    int i = blockIdx.x * 256 + threadIdx.x;   // B*S*64
    int d = i & 63;
    int tok = i >> 6;
    int s = tok & (S_ - 1);
    int b = tok >> 10;
    float pos = (float)(start_pos[b] + s);
    float freq = __expf(-(float)d * (9.210340371976184f / 64.f));   // 10000^(-d/64)
    float ang = pos * freq;
    tab[tok * 128 + d]      = cosf(ang);
    tab[tok * 128 + 64 + d] = sinf(ang);
}

// ---------------- in-place NeoX rotary on bf16 [tok][*][128] ----------------
template<int LOGH, int STRIDE>
__global__ __launch_bounds__(256) void rope_apply_kernel(unsigned short* __restrict__ t,
                                                         const float* __restrict__ tab) {
    int i = blockIdx.x * 256 + threadIdx.x;   // B*S*Hn*64
    int d = i & 63;
    int h = (i >> 6) & ((1 << LOGH) - 1);
    int tok = i >> (6 + LOGH);
    size_t base = (size_t)tok * STRIDE + (size_t)h * 128;
    float c  = tab[tok * 128 + d];
    float sn = tab[tok * 128 + 64 + d];
    float a = bf2f(t[base + d]);
    float b = bf2f(t[base + 64 + d]);
    t[base + d]      = f2bf(a * c - b * sn);
    t[base + 64 + d] = f2bf(b * c + a * sn);
}

// ---------------- flash attention: 1 wave per (b, h, 32-row q tile) ----------------
// KV combined layout: KVb[tok][0:1024]=K heads, [1024:2048]=V heads.
__global__ __launch_bounds__(64) void attn_fwd(
    const unsigned short* __restrict__ Qb,   // [B*S][4096]
    const unsigned short* __restrict__ KVb,  // [B*S][2048]
    unsigned short* __restrict__ Ob)         // [B*S][4096]
{
    const int nQT = S_ / 32;
    const int qt = nQT - 1 - blockIdx.y;     // heavy-first
    const int h = blockIdx.x, b = blockIdx.z;
    const int kvh = h >> 2;
    const int lane = threadIdx.x;
    const int r = lane & 15, g = lane >> 4;
    __shared__ unsigned short P_lds[32][40];

    const int qrow0 = qt * 32;
    const unsigned short* Qp = Qb + ((size_t)(b * S_) + qrow0) * 4096 + h * 128;
    bf16x8_t qf[2][4];
#pragma unroll
    for (int q2 = 0; q2 < 2; ++q2)
#pragma unroll
        for (int kk = 0; kk < 4; ++kk)
            qf[q2][kk] = *reinterpret_cast<const bf16x8_t*>(
                &Qp[(size_t)(q2 * 16 + r) * 4096 + kk * 32 + g * 8]);

    const f32x4_t zero = {0.f, 0.f, 0.f, 0.f};
    f32x4_t o[2][8];
#pragma unroll
    for (int q2 = 0; q2 < 2; ++q2)
#pragma unroll
        for (int n = 0; n < 8; ++n) o[q2][n] = zero;
    float m_[2][4], s_[2][4];
#pragma unroll
    for (int q2 = 0; q2 < 2; ++q2)
#pragma unroll
        for (int j = 0; j < 4; ++j) { m_[q2][j] = -1e30f; s_[q2][j] = 0.f; }

    const float scale = 0.08838834764831845f;   // 1/sqrt(128)
    const unsigned short* Kp = KVb + (size_t)(b * S_) * 2048 + kvh * 128;
    const unsigned short* Vp = Kp + 1024;
    const int ntiles = qt + 1;

    for (int t = 0; t < ntiles; ++t) {
        const int k0 = t << 5;
        // ---- QK^T: 32 kv cols (two 16-col halves), shared K frags ----
        f32x4_t sc[2][2];
        sc[0][0] = zero; sc[0][1] = zero; sc[1][0] = zero; sc[1][1] = zero;
#pragma unroll
        for (int kk = 0; kk < 4; ++kk) {
            bf16x8_t kf0 = *reinterpret_cast<const bf16x8_t*>(
                &Kp[(size_t)(k0 + r) * 2048 + kk * 32 + g * 8]);
            bf16x8_t kf1 = *reinterpret_cast<const bf16x8_t*>(
                &Kp[(size_t)(k0 + 16 + r) * 2048 + kk * 32 + g * 8]);
#pragma unroll
            for (int q2 = 0; q2 < 2; ++q2) {
                sc[q2][0] = __builtin_amdgcn_mfma_f32_16x16x32_bf16(qf[q2][kk], kf0, sc[q2][0], 0, 0, 0);
                sc[q2][1] = __builtin_amdgcn_mfma_f32_16x16x32_bf16(qf[q2][kk], kf1, sc[q2][1], 0, 0, 0);
            }
        }
        // ---- online softmax (row q2*16+g*4+j; cols r, 16+r) ----
        float al[2][4];
#pragma unroll
        for (int q2 = 0; q2 < 2; ++q2)
#pragma unroll
            for (int j = 0; j < 4; ++j) {
                int row = qrow0 + q2 * 16 + g * 4 + j;
                float v0 = sc[q2][0][j] * scale + ((k0 + r)      > row ? -1e9f : 0.f);
                float v1 = sc[q2][1][j] * scale + ((k0 + 16 + r) > row ? -1e9f : 0.f);
                float mx = fmaxf(v0, v1);
#pragma unroll
                for (int off = 1; off < 16; off <<= 1)
                    mx = fmaxf(mx, __shfl_xor(mx, off));
                float mn = fmaxf(m_[q2][j], mx);
                al[q2][j] = __expf(m_[q2][j] - mn);
                float p0 = __expf(v0 - mn);
                float p1 = __expf(v1 - mn);
                float rs = p0 + p1;
#pragma unroll
                for (int off = 1; off < 16; off <<= 1)
                    rs += __shfl_xor(rs, off);
                s_[q2][j] = s_[q2][j] * al[q2][j] + rs;
                m_[q2][j] = mn;
                P_lds[q2 * 16 + g * 4 + j][r]      = f2bf(p0);
                P_lds[q2 * 16 + g * 4 + j][16 + r] = f2bf(p1);
            }
#pragma unroll
        for (int q2 = 0; q2 < 2; ++q2)
#pragma unroll
            for (int n = 0; n < 8; ++n)
#pragma unroll
                for (int j = 0; j < 4; ++j)
                    o[q2][n][j] *= al[q2][j];
        __syncthreads();
        bf16x8_t pa[2];
        pa[0] = *reinterpret_cast<const bf16x8_t*>(&P_lds[r][g * 8]);
        pa[1] = *reinterpret_cast<const bf16x8_t*>(&P_lds[16 + r][g * 8]);
        // ---- PV: direct-global V B-fragments (L2-resident), shared across q2 ----
#pragma unroll
        for (int n = 0; n < 8; ++n) {
            union { bf16x8_t v; unsigned short u[8]; } vb;
#pragma unroll
            for (int j = 0; j < 8; ++j)
                vb.u[j] = Vp[(size_t)(k0 + g * 8 + j) * 2048 + n * 16 + r];
#pragma unroll
            for (int q2 = 0; q2 < 2; ++q2)
                o[q2][n] = __builtin_amdgcn_mfma_f32_16x16x32_bf16(pa[q2], vb.v, o[q2][n], 0, 0, 0);
        }
        __syncthreads();
    }
    // ---- epilogue ----
    unsigned short* Op = Ob + ((size_t)(b * S_) + qrow0) * 4096 + h * 128;
#pragma unroll
    for (int q2 = 0; q2 < 2; ++q2)
#pragma unroll
        for (int n = 0; n < 8; ++n)
#pragma unroll
            for (int j = 0; j < 4; ++j) {
                float val = o[q2][n][j] / s_[q2][j];
                Op[(size_t)(q2 * 16 + g * 4 + j) * 4096 + n * 16 + r] = f2bf(val);
            }
}

// ---------------- launcher ----------------
extern "C" void kernel_launch(void* const* d_in, const int* in_sizes, int n_in,
                              void* d_out, int out_size, void* d_ws, size_t ws_size,
                              hipStream_t stream)
{
    const float* x  = (const float*)d_in[0];
    const float* wq = (const float*)d_in[2];
    const float* wk = (const float*)d_in[3];
    const float* wv = (const float*)d_in[4];
    const float* wo = (const float*)d_in[5];
    const int* start_pos = (const int*)d_in[10];

    char* ws = (char*)d_ws;
    unsigned short* xb  = (unsigned short*)(ws);                   // 16 MB  x bf16 (= ab later)
    unsigned short* qb  = (unsigned short*)(ws + (16u << 20));     // 16 MB  Q
    unsigned short* kvb = (unsigned short*)(ws + (32u << 20));     //  8 MB  K|V combined
    unsigned short* wT  = (unsigned short*)(ws + (40u << 20));     // 16 MB  weight^T panel
    float*          tb  = (float*)(ws + (56u << 20));              //  1 MB  rope table
    unsigned short* ab  = xb;                                      // attn out reuses xb

    // 1) x -> bf16
    cvt_f32_bf16<<<8192, 256, 0, stream>>>(x, xb, (B_ * S_ * HID_) / 4);

    // 2) Q projection in two N=2048 panels (wT reused)
    tcvt<<<dim3(64, 128), 256, 0, stream>>>(wq, wT, HID_, HID_);
    gemm_tt<true><<<dim3(16, 16), 256, 0, stream>>>(xb, wT, qb, 4096, HID_);
    tcvt<<<dim3(64, 128), 256, 0, stream>>>(wq + 2048, wT, HID_, HID_);
    gemm_tt<true><<<dim3(16, 16), 256, 0, stream>>>(xb, wT, qb + 2048, 4096, HID_);

    // 3) K,V fused projection (N=2048): wT rows 0-1023 = wk^T, 1024-2047 = wv^T
    tcvt<<<dim3(32, 128), 256, 0, stream>>>(wk, wT, 1024, HID_);
    tcvt<<<dim3(32, 128), 256, 0, stream>>>(wv, wT + (size_t)1024 * HID_, 1024, HID_);
    gemm_tt<true><<<dim3(16, 16), 256, 0, stream>>>(xb, wT, kvb, 2048, HID_);

    // 4) rotary
    rope_table_kernel<<<512, 256, 0, stream>>>(start_pos, tb);
    rope_apply_kernel<5, 4096><<<16384, 256, 0, stream>>>(qb, tb);
    rope_apply_kernel<3, 2048><<<4096, 256, 0, stream>>>(kvb, tb);

    // 5) causal GQA flash attention
    attn_fwd<<<dim3(H_, S_ / 32, B_), 64, 0, stream>>>(qb, kvb, ab);

    // 6) output projection in two N=2048 panels -> fp32 d_out
    tcvt<<<dim3(64, 128), 256, 0, stream>>>(wo, wT, HID_, HID_);
    gemm_tt<false><<<dim3(16, 16), 256, 0, stream>>>(ab, wT, (float*)d_out, 4096, HID_);
    tcvt<<<dim3(64, 128), 256, 0, stream>>>(wo + 2048, wT, HID_, HID_);
    gemm_tt<false><<<dim3(16, 16), 256, 0, stream>>>(ab, wT, (float*)d_out + 2048, 4096, HID_);
}

// Round 4
// 629.228 us; speedup vs baseline: 1.6662x; 1.2838x over previous
//
#include <hip/hip_runtime.h>
#include <hip/hip_bf16.h>

#define B_    2
#define S_    1024
#define HID_  4096
#define H_    32
#define HKV_  8
#define HD_   128

typedef __attribute__((ext_vector_type(8))) short   bf16x8_t;
typedef __attribute__((ext_vector_type(4))) float   f32x4_t;

__device__ __forceinline__ unsigned short f2bf(float f) {
    union { float f; unsigned u; } v; v.f = f;
    unsigned r = v.u + 0x7fffu + ((v.u >> 16) & 1u);
    return (unsigned short)(r >> 16);
}
__device__ __forceinline__ float bf2f(unsigned short u) {
    union { unsigned u; float f; } v; v.u = ((unsigned)u) << 16;
    return v.f;
}

__device__ __forceinline__ void gload_lds16(const void* g, void* l) {
    __builtin_amdgcn_global_load_lds(
        (const __attribute__((address_space(1))) unsigned int*)g,
        (__attribute__((address_space(3))) unsigned int*)l, 16, 0, 0);
}

// ---------------- convert fp32 -> bf16 (vectorized) ----------------
__global__ __launch_bounds__(256) void cvt_f32_bf16(const float* __restrict__ in,
                                                    unsigned short* __restrict__ out,
                                                    int n4) {
    int i = blockIdx.x * 256 + threadIdx.x;
    if (i >= n4) return;
    float4 v = reinterpret_cast<const float4*>(in)[i];
    uint2 p;
    p.x = (unsigned)f2bf(v.x) | ((unsigned)f2bf(v.y) << 16);
    p.y = (unsigned)f2bf(v.z) | ((unsigned)f2bf(v.w) << 16);
    reinterpret_cast<uint2*>(out)[i] = p;
}

// ---------------- transpose+convert: W fp32 [K][ldW] -> Wt bf16 [n][K] ----------------
__global__ __launch_bounds__(256) void tcvt(const float* __restrict__ W,
                                            unsigned short* __restrict__ Wt,
                                            int ldW, int Kdim) {
    __shared__ unsigned short L[32][36];
    const int t = threadIdx.x;
    const int kb = blockIdx.y, nb = blockIdx.x;
    {
        int kr = t >> 3, nc = (t & 7) * 4;
        float4 v = *reinterpret_cast<const float4*>(&W[(size_t)(kb * 32 + kr) * ldW + nb * 32 + nc]);
        L[nc + 0][kr] = f2bf(v.x);
        L[nc + 1][kr] = f2bf(v.y);
        L[nc + 2][kr] = f2bf(v.z);
        L[nc + 3][kr] = f2bf(v.w);
    }
    __syncthreads();
    {
        int nr = t >> 3, kc = (t & 7) * 4;
        uint2 o;
        o.x = (unsigned)L[nr][kc + 0] | ((unsigned)L[nr][kc + 1] << 16);
        o.y = (unsigned)L[nr][kc + 2] | ((unsigned)L[nr][kc + 3] << 16);
        *reinterpret_cast<uint2*>(&Wt[(size_t)(nb * 32 + nr) * Kdim + kb * 32 + kc]) = o;
    }
}

// ---------------- GEMM (m97 structure): C = A[M][K] @ Bt[N][K]^T ----------------
template<bool OUT_BF16>
__global__ __launch_bounds__(256) void gemm_tt(
    const unsigned short* __restrict__ A,
    const unsigned short* __restrict__ Bt,
    void* __restrict__ Cm,
    int ldc, int K)
{
    __shared__ unsigned short As[128 * 32];
    __shared__ unsigned short Bs[128 * 32];
    const int tid  = threadIdx.x;
    const int lane = tid & 63;
    const int w    = tid >> 6;
    const int wm   = w >> 1, wn = w & 1;
    const int r    = lane & 15, g = lane >> 4;
    const int m0   = blockIdx.y * 128, n0 = blockIdx.x * 128;

    const int c0 = w * 128 + lane;
    const int c1 = c0 + 64;
    const int r0 = c0 >> 2, col0 = (c0 & 3) << 3;
    const int r1 = c1 >> 2, col1 = (c1 & 3) << 3;

    const f32x4_t zero = {0.f, 0.f, 0.f, 0.f};
    f32x4_t acc[4][4];
#pragma unroll
    for (int i = 0; i < 4; ++i)
#pragma unroll
        for (int j = 0; j < 4; ++j) acc[i][j] = zero;

    for (int k0 = 0; k0 < K; k0 += 32) {
        __syncthreads();
        gload_lds16(&A [(size_t)(m0 + r0) * K + k0 + col0], As + (size_t)(w * 2 + 0) * 512);
        gload_lds16(&A [(size_t)(m0 + r1) * K + k0 + col1], As + (size_t)(w * 2 + 1) * 512);
        gload_lds16(&Bt[(size_t)(n0 + r0) * K + k0 + col0], Bs + (size_t)(w * 2 + 0) * 512);
        gload_lds16(&Bt[(size_t)(n0 + r1) * K + k0 + col1], Bs + (size_t)(w * 2 + 1) * 512);
        __syncthreads();

        bf16x8_t af[4], bfr[4];
#pragma unroll
        for (int m = 0; m < 4; ++m)
            af[m] = *reinterpret_cast<const bf16x8_t*>(&As[(wm * 64 + m * 16 + r) * 32 + g * 8]);
#pragma unroll
        for (int n = 0; n < 4; ++n)
            bfr[n] = *reinterpret_cast<const bf16x8_t*>(&Bs[(wn * 64 + n * 16 + r) * 32 + g * 8]);
#pragma unroll
        for (int m = 0; m < 4; ++m)
#pragma unroll
            for (int n = 0; n < 4; ++n)
                acc[m][n] = __builtin_amdgcn_mfma_f32_16x16x32_bf16(af[m], bfr[n], acc[m][n], 0, 0, 0);
    }

#pragma unroll
    for (int m = 0; m < 4; ++m)
#pragma unroll
        for (int n = 0; n < 4; ++n)
#pragma unroll
            for (int j = 0; j < 4; ++j) {
                int row = m0 + wm * 64 + m * 16 + g * 4 + j;
                int col = n0 + wn * 64 + n * 16 + r;
                if constexpr (OUT_BF16)
                    reinterpret_cast<unsigned short*>(Cm)[(size_t)row * ldc + col] = f2bf(acc[m][n][j]);
                else
                    reinterpret_cast<float*>(Cm)[(size_t)row * ldc + col] = acc[m][n][j];
            }
}

// ---------------- KV GEMM: cols<1024 -> Kb[tok][1024]; cols>=1024 -> VT[b*1024+d][tok] ----------------
__global__ __launch_bounds__(256) void gemm_kv(
    const unsigned short* __restrict__ A,    // [2048][4096]
    const unsigned short* __restrict__ Bt,   // [2048][4096] (wk^T | wv^T)
    unsigned short* __restrict__ Kb,         // [2048][1024]
    unsigned short* __restrict__ VT,         // [2048][1024] transposed V
    int K)
{
    __shared__ unsigned short As[128 * 32];
    __shared__ unsigned short Bs[128 * 32];
    const int tid  = threadIdx.x;
    const int lane = tid & 63;
    const int w    = tid >> 6;
    const int wm   = w >> 1, wn = w & 1;
    const int r    = lane & 15, g = lane >> 4;
    const int m0   = blockIdx.y * 128, n0 = blockIdx.x * 128;

    const int c0 = w * 128 + lane;
    const int c1 = c0 + 64;
    const int r0 = c0 >> 2, col0 = (c0 & 3) << 3;
    const int r1 = c1 >> 2, col1 = (c1 & 3) << 3;

    const f32x4_t zero = {0.f, 0.f, 0.f, 0.f};
    f32x4_t acc[4][4];
#pragma unroll
    for (int i = 0; i < 4; ++i)
#pragma unroll
        for (int j = 0; j < 4; ++j) acc[i][j] = zero;

    for (int k0 = 0; k0 < K; k0 += 32) {
        __syncthreads();
        gload_lds16(&A [(size_t)(m0 + r0) * K + k0 + col0], As + (size_t)(w * 2 + 0) * 512);
        gload_lds16(&A [(size_t)(m0 + r1) * K + k0 + col1], As + (size_t)(w * 2 + 1) * 512);
        gload_lds16(&Bt[(size_t)(n0 + r0) * K + k0 + col0], Bs + (size_t)(w * 2 + 0) * 512);
        gload_lds16(&Bt[(size_t)(n0 + r1) * K + k0 + col1], Bs + (size_t)(w * 2 + 1) * 512);
        __syncthreads();

        bf16x8_t af[4], bfr[4];
#pragma unroll
        for (int m = 0; m < 4; ++m)
            af[m] = *reinterpret_cast<const bf16x8_t*>(&As[(wm * 64 + m * 16 + r) * 32 + g * 8]);
#pragma unroll
        for (int n = 0; n < 4; ++n)
            bfr[n] = *reinterpret_cast<const bf16x8_t*>(&Bs[(wn * 64 + n * 16 + r) * 32 + g * 8]);
#pragma unroll
        for (int m = 0; m < 4; ++m)
#pragma unroll
            for (int n = 0; n < 4; ++n)
                acc[m][n] = __builtin_amdgcn_mfma_f32_16x16x32_bf16(af[m], bfr[n], acc[m][n], 0, 0, 0);
    }

    const bool isV = (n0 >= 1024);   // whole 128-tile on one side
#pragma unroll
    for (int m = 0; m < 4; ++m)
#pragma unroll
        for (int n = 0; n < 4; ++n) {
            int col  = n0 + wn * 64 + n * 16 + r;
            int row0 = m0 + wm * 64 + m * 16 + g * 4;
            if (!isV) {
#pragma unroll
                for (int j = 0; j < 4; ++j)
                    Kb[(size_t)(row0 + j) * 1024 + col] = f2bf(acc[m][n][j]);
            } else {
                int d = col - 1024;            // kvh*128 + dd
                int b = row0 >> 10, tokl = row0 & 1023;
                uint2 o;
                o.x = (unsigned)f2bf(acc[m][n][0]) | ((unsigned)f2bf(acc[m][n][1]) << 16);
                o.y = (unsigned)f2bf(acc[m][n][2]) | ((unsigned)f2bf(acc[m][n][3]) << 16);
                *reinterpret_cast<uint2*>(&VT[(size_t)(b * 1024 + d) * 1024 + tokl]) = o;
            }
        }
}

// ---------------- rope table: tab[tok][0:64]=cos, [64:128]=sin ----------------
__global__ __launch_bounds__(256) void rope_table_kernel(const int* __restrict__ start_pos,
                                                         float* __restrict__ tab) {
    int i = blockIdx.x * 256 + threadIdx.x;   // B*S*64
    int d = i & 63;
    int tok = i >> 6;
    int s = tok & (S_ - 1);
    int b = tok >> 10;
    float pos = (float)(start_pos[b] + s);
    float freq = __expf(-(float)d * (9.210340371976184f / 64.f));   // 10000^(-d/64)
    float ang = pos * freq;
    tab[tok * 128 + d]      = cosf(ang);
    tab[tok * 128 + 64 + d] = sinf(ang);
}

// ---------------- in-place NeoX rotary on bf16 [tok][*][128] ----------------
template<int LOGH, int STRIDE>
__global__ __launch_bounds__(256) void rope_apply_kernel(unsigned short* __restrict__ t,
                                                         const float* __restrict__ tab) {
    int i = blockIdx.x * 256 + threadIdx.x;   // B*S*Hn*64
    int d = i & 63;
    int h = (i >> 6) & ((1 << LOGH) - 1);
    int tok = i >> (6 + LOGH);
    size_t base = (size_t)tok * STRIDE + (size_t)h * 128;
    float c  = tab[tok * 128 + d];
    float sn = tab[tok * 128 + 64 + d];
    float a = bf2f(t[base + d]);
    float b = bf2f(t[base + 64 + d]);
    t[base + d]      = f2bf(a * c - b * sn);
    t[base + 64 + d] = f2bf(b * c + a * sn);
}

// ---------------- flash attention: 1 wave per (b, h, 32-row q tile) ----------------
__global__ __launch_bounds__(64) void attn_fwd(
    const unsigned short* __restrict__ Qb,   // [2048][4096]
    const unsigned short* __restrict__ Kb,   // [2048][1024]
    const unsigned short* __restrict__ VT,   // [2048][1024]  (b*1024+d rows, tok cols)
    unsigned short* __restrict__ Ob)         // [2048][4096]
{
    const int nQT = S_ / 32;
    const int qt = nQT - 1 - blockIdx.y;     // heavy-first
    const int h = blockIdx.x, b = blockIdx.z;
    const int kvh = h >> 2;
    const int lane = threadIdx.x;
    const int r = lane & 15, g = lane >> 4;
    __shared__ unsigned short P_lds[32][40];

    const int qrow0 = qt * 32;
    const unsigned short* Qp = Qb + ((size_t)(b * S_) + qrow0) * 4096 + h * 128;
    bf16x8_t qf[2][4];
#pragma unroll
    for (int q2 = 0; q2 < 2; ++q2)
#pragma unroll
        for (int kk = 0; kk < 4; ++kk)
            qf[q2][kk] = *reinterpret_cast<const bf16x8_t*>(
                &Qp[(size_t)(q2 * 16 + r) * 4096 + kk * 32 + g * 8]);

    const f32x4_t zero = {0.f, 0.f, 0.f, 0.f};
    f32x4_t o[2][8];
#pragma unroll
    for (int q2 = 0; q2 < 2; ++q2)
#pragma unroll
        for (int n = 0; n < 8; ++n) o[q2][n] = zero;
    float m_[2][4], s_[2][4];
#pragma unroll
    for (int q2 = 0; q2 < 2; ++q2)
#pragma unroll
        for (int j = 0; j < 4; ++j) { m_[q2][j] = -1e30f; s_[q2][j] = 0.f; }

    const float scale = 0.08838834764831845f;   // 1/sqrt(128)
    const unsigned short* Kp = Kb + (size_t)(b * S_) * 1024 + kvh * 128;
    const unsigned short* Vt = VT + ((size_t)(b * 1024) + kvh * 128) * 1024;
    const int ntiles = qt + 1;

    for (int t = 0; t < ntiles; ++t) {
        const int k0 = t << 5;
        // ---- QK^T: 32 kv cols (two 16-col halves), shared K frags ----
        f32x4_t sc[2][2];
        sc[0][0] = zero; sc[0][1] = zero; sc[1][0] = zero; sc[1][1] = zero;
#pragma unroll
        for (int kk = 0; kk < 4; ++kk) {
            bf16x8_t kf0 = *reinterpret_cast<const bf16x8_t*>(
                &Kp[(size_t)(k0 + r) * 1024 + kk * 32 + g * 8]);
            bf16x8_t kf1 = *reinterpret_cast<const bf16x8_t*>(
                &Kp[(size_t)(k0 + 16 + r) * 1024 + kk * 32 + g * 8]);
#pragma unroll
            for (int q2 = 0; q2 < 2; ++q2) {
                sc[q2][0] = __builtin_amdgcn_mfma_f32_16x16x32_bf16(qf[q2][kk], kf0, sc[q2][0], 0, 0, 0);
                sc[q2][1] = __builtin_amdgcn_mfma_f32_16x16x32_bf16(qf[q2][kk], kf1, sc[q2][1], 0, 0, 0);
            }
        }
        // ---- V^T B-fragments: contiguous 16B vector loads (issued before softmax) ----
        bf16x8_t vf[8];
#pragma unroll
        for (int n = 0; n < 8; ++n)
            vf[n] = *reinterpret_cast<const bf16x8_t*>(
                &Vt[(size_t)(n * 16 + r) * 1024 + k0 + g * 8]);
        // ---- online softmax (row q2*16+g*4+j; cols r, 16+r) ----
        float al[2][4];
#pragma unroll
        for (int q2 = 0; q2 < 2; ++q2)
#pragma unroll
            for (int j = 0; j < 4; ++j) {
                int row = qrow0 + q2 * 16 + g * 4 + j;
                float v0 = sc[q2][0][j] * scale + ((k0 + r)      > row ? -1e9f : 0.f);
                float v1 = sc[q2][1][j] * scale + ((k0 + 16 + r) > row ? -1e9f : 0.f);
                float mx = fmaxf(v0, v1);
#pragma unroll
                for (int off = 1; off < 16; off <<= 1)
                    mx = fmaxf(mx, __shfl_xor(mx, off));
                float mn = fmaxf(m_[q2][j], mx);
                al[q2][j] = __expf(m_[q2][j] - mn);
                float p0 = __expf(v0 - mn);
                float p1 = __expf(v1 - mn);
                float rs = p0 + p1;
#pragma unroll
                for (int off = 1; off < 16; off <<= 1)
                    rs += __shfl_xor(rs, off);
                s_[q2][j] = s_[q2][j] * al[q2][j] + rs;
                m_[q2][j] = mn;
                P_lds[q2 * 16 + g * 4 + j][r]      = f2bf(p0);
                P_lds[q2 * 16 + g * 4 + j][16 + r] = f2bf(p1);
            }
#pragma unroll
        for (int q2 = 0; q2 < 2; ++q2)
#pragma unroll
            for (int n = 0; n < 8; ++n)
#pragma unroll
                for (int j = 0; j < 4; ++j)
                    o[q2][n][j] *= al[q2][j];
        __syncthreads();
        bf16x8_t pa[2];
        pa[0] = *reinterpret_cast<const bf16x8_t*>(&P_lds[r][g * 8]);
        pa[1] = *reinterpret_cast<const bf16x8_t*>(&P_lds[16 + r][g * 8]);
        // ---- PV: O += P @ V with vector-loaded V^T fragments ----
#pragma unroll
        for (int n = 0; n < 8; ++n)
#pragma unroll
            for (int q2 = 0; q2 < 2; ++q2)
                o[q2][n] = __builtin_amdgcn_mfma_f32_16x16x32_bf16(pa[q2], vf[n], o[q2][n], 0, 0, 0);
        __syncthreads();
    }
    // ---- epilogue ----
    unsigned short* Op = Ob + ((size_t)(b * S_) + qrow0) * 4096 + h * 128;
#pragma unroll
    for (int q2 = 0; q2 < 2; ++q2)
#pragma unroll
        for (int n = 0; n < 8; ++n)
#pragma unroll
            for (int j = 0; j < 4; ++j) {
                float val = o[q2][n][j] / s_[q2][j];
                Op[(size_t)(q2 * 16 + g * 4 + j) * 4096 + n * 16 + r] = f2bf(val);
            }
}

// ---------------- launcher ----------------
extern "C" void kernel_launch(void* const* d_in, const int* in_sizes, int n_in,
                              void* d_out, int out_size, void* d_ws, size_t ws_size,
                              hipStream_t stream)
{
    const float* x  = (const float*)d_in[0];
    const float* wq = (const float*)d_in[2];
    const float* wk = (const float*)d_in[3];
    const float* wv = (const float*)d_in[4];
    const float* wo = (const float*)d_in[5];
    const int* start_pos = (const int*)d_in[10];

    char* ws = (char*)d_ws;
    unsigned short* xb  = (unsigned short*)(ws);                   // [0,16M)  x bf16, later attn out
    unsigned short* qb  = (unsigned short*)(ws + (16u << 20));     // [16,32M) Q
    unsigned short* kb  = (unsigned short*)(ws + (32u << 20));     // [32,36M) K
    unsigned short* vT  = (unsigned short*)(ws + (36u << 20));     // [36,40M) V^T
    unsigned short* wT  = (unsigned short*)(ws + (40u << 20));     // [40,56M) wk^T|wv^T panel
    float*          tb  = (float*)(ws + (56u << 20));              // [56,57M) rope table
    unsigned short* ab  = xb;                                      // attn out reuses xb
    unsigned short* wqT = (unsigned short*)d_out;                  // 32 MB scratch until final store
    unsigned short* woT = qb;                                      // [16,48M): 32 MB, free after attn

    // 1) x -> bf16
    cvt_f32_bf16<<<8192, 256, 0, stream>>>(x, xb, (B_ * S_ * HID_) / 4);

    // 2) Q projection, single N=4096 dispatch (wq^T staged in d_out)
    tcvt<<<dim3(128, 128), 256, 0, stream>>>(wq, wqT, HID_, HID_);
    gemm_tt<true><<<dim3(32, 16), 256, 0, stream>>>(xb, wqT, qb, 4096, HID_);

    // 3) K,V fused projection (N=2048); V written transposed
    tcvt<<<dim3(32, 128), 256, 0, stream>>>(wk, wT, 1024, HID_);
    tcvt<<<dim3(32, 128), 256, 0, stream>>>(wv, wT + (size_t)1024 * HID_, 1024, HID_);
    gemm_kv<<<dim3(16, 16), 256, 0, stream>>>(xb, wT, kb, vT, HID_);

    // 4) rotary (V untouched)
    rope_table_kernel<<<512, 256, 0, stream>>>(start_pos, tb);
    rope_apply_kernel<5, 4096><<<16384, 256, 0, stream>>>(qb, tb);
    rope_apply_kernel<3, 1024><<<4096, 256, 0, stream>>>(kb, tb);

    // 5) causal GQA flash attention
    attn_fwd<<<dim3(H_, S_ / 32, B_), 64, 0, stream>>>(qb, kb, vT, ab);

    // 6) output projection, single N=4096 dispatch (wo^T staged over qb/kb/vT/wT)
    tcvt<<<dim3(128, 128), 256, 0, stream>>>(wo, woT, HID_, HID_);
    gemm_tt<false><<<dim3(32, 16), 256, 0, stream>>>(ab, woT, (float*)d_out, 4096, HID_);
}

// Round 5
// 566.809 us; speedup vs baseline: 1.8497x; 1.1101x over previous
//
#include <hip/hip_runtime.h>
#include <hip/hip_bf16.h>

#define B_    2
#define S_    1024
#define HID_  4096
#define H_    32
#define HKV_  8
#define HD_   128

typedef __attribute__((ext_vector_type(8))) short   bf16x8_t;
typedef __attribute__((ext_vector_type(4))) float   f32x4_t;

__device__ __forceinline__ unsigned short f2bf(float f) {
    union { float f; unsigned u; } v; v.f = f;
    unsigned r = v.u + 0x7fffu + ((v.u >> 16) & 1u);
    return (unsigned short)(r >> 16);
}
__device__ __forceinline__ float bf2f(unsigned short u) {
    union { unsigned u; float f; } v; v.u = ((unsigned)u) << 16;
    return v.f;
}

__device__ __forceinline__ void gload_lds16(const void* g, void* l) {
    __builtin_amdgcn_global_load_lds(
        (const __attribute__((address_space(1))) unsigned int*)g,
        (__attribute__((address_space(3))) unsigned int*)l, 16, 0, 0);
}

// ---------------- convert fp32 -> bf16 (vectorized) ----------------
__global__ __launch_bounds__(256) void cvt_f32_bf16(const float* __restrict__ in,
                                                    unsigned short* __restrict__ out,
                                                    int n4) {
    int i = blockIdx.x * 256 + threadIdx.x;
    if (i >= n4) return;
    float4 v = reinterpret_cast<const float4*>(in)[i];
    uint2 p;
    p.x = (unsigned)f2bf(v.x) | ((unsigned)f2bf(v.y) << 16);
    p.y = (unsigned)f2bf(v.z) | ((unsigned)f2bf(v.w) << 16);
    reinterpret_cast<uint2*>(out)[i] = p;
}

// ---------------- transpose+convert: W fp32 [K][ldW] -> Wt bf16 [n][K] ----------------
__global__ __launch_bounds__(256) void tcvt(const float* __restrict__ W,
                                            unsigned short* __restrict__ Wt,
                                            int ldW, int Kdim) {
    __shared__ unsigned short L[32][36];
    const int t = threadIdx.x;
    const int kb = blockIdx.y, nb = blockIdx.x;
    {
        int kr = t >> 3, nc = (t & 7) * 4;
        float4 v = *reinterpret_cast<const float4*>(&W[(size_t)(kb * 32 + kr) * ldW + nb * 32 + nc]);
        L[nc + 0][kr] = f2bf(v.x);
        L[nc + 1][kr] = f2bf(v.y);
        L[nc + 2][kr] = f2bf(v.z);
        L[nc + 3][kr] = f2bf(v.w);
    }
    __syncthreads();
    {
        int nr = t >> 3, kc = (t & 7) * 4;
        uint2 o;
        o.x = (unsigned)L[nr][kc + 0] | ((unsigned)L[nr][kc + 1] << 16);
        o.y = (unsigned)L[nr][kc + 2] | ((unsigned)L[nr][kc + 3] << 16);
        *reinterpret_cast<uint2*>(&Wt[(size_t)(nb * 32 + nr) * Kdim + kb * 32 + kc]) = o;
    }
}

// ---------------- O-proj GEMM: 2-phase dbuf + chunk swizzle + XCD remap ----------------
template<bool OUT_BF16>
__global__ __launch_bounds__(256) void gemm_tt(
    const unsigned short* __restrict__ A,
    const unsigned short* __restrict__ Bt,
    void* __restrict__ Cm,
    int ldc, int K)
{
    __shared__ unsigned short As[2][128 * 32];
    __shared__ unsigned short Bs[2][128 * 32];
    const int tid  = threadIdx.x;
    const int lane = tid & 63;
    const int w    = tid >> 6;
    const int wm   = w >> 1, wn = w & 1;
    const int r    = lane & 15, g = lane >> 4;

    // XCD-chunked block remap (nwg % 8 == 0)
    const int nwg = gridDim.x * gridDim.y;
    const int D   = blockIdx.y * gridDim.x + blockIdx.x;
    const int L   = (D & 7) * (nwg >> 3) + (D >> 3);
    const int m0  = (L / gridDim.x) * 128, n0 = (L % gridDim.x) * 128;

    const int c0 = w * 128 + lane;
    const int c1 = c0 + 64;
    const int r0 = c0 >> 2, col0 = (((c0 & 3) ^ (r0 & 3)) << 3);
    const int r1 = c1 >> 2, col1 = (((c1 & 3) ^ (r1 & 3)) << 3);
    const int sw = (g ^ (r & 3)) << 3;          // swizzled read chunk (shorts)

    const f32x4_t zero = {0.f, 0.f, 0.f, 0.f};
    f32x4_t acc[4][4];
#pragma unroll
    for (int i = 0; i < 4; ++i)
#pragma unroll
        for (int j = 0; j < 4; ++j) acc[i][j] = zero;

    // prologue stage
    gload_lds16(&A [(size_t)(m0 + r0) * K + col0], &As[0][(w * 2 + 0) * 512]);
    gload_lds16(&A [(size_t)(m0 + r1) * K + col1], &As[0][(w * 2 + 1) * 512]);
    gload_lds16(&Bt[(size_t)(n0 + r0) * K + col0], &Bs[0][(w * 2 + 0) * 512]);
    gload_lds16(&Bt[(size_t)(n0 + r1) * K + col1], &Bs[0][(w * 2 + 1) * 512]);
    __syncthreads();

    int cur = 0;
    for (int k0 = 0; k0 < K; k0 += 32) {
        if (k0 + 32 < K) {
            const int nk = k0 + 32, nb = cur ^ 1;
            gload_lds16(&A [(size_t)(m0 + r0) * K + nk + col0], &As[nb][(w * 2 + 0) * 512]);
            gload_lds16(&A [(size_t)(m0 + r1) * K + nk + col1], &As[nb][(w * 2 + 1) * 512]);
            gload_lds16(&Bt[(size_t)(n0 + r0) * K + nk + col0], &Bs[nb][(w * 2 + 0) * 512]);
            gload_lds16(&Bt[(size_t)(n0 + r1) * K + nk + col1], &Bs[nb][(w * 2 + 1) * 512]);
        }
        bf16x8_t af[4], bfr[4];
#pragma unroll
        for (int m = 0; m < 4; ++m)
            af[m] = *reinterpret_cast<const bf16x8_t*>(&As[cur][(wm * 64 + m * 16 + r) * 32 + sw]);
#pragma unroll
        for (int n = 0; n < 4; ++n)
            bfr[n] = *reinterpret_cast<const bf16x8_t*>(&Bs[cur][(wn * 64 + n * 16 + r) * 32 + sw]);
#pragma unroll
        for (int m = 0; m < 4; ++m)
#pragma unroll
            for (int n = 0; n < 4; ++n)
                acc[m][n] = __builtin_amdgcn_mfma_f32_16x16x32_bf16(af[m], bfr[n], acc[m][n], 0, 0, 0);
        __syncthreads();
        cur ^= 1;
    }

#pragma unroll
    for (int m = 0; m < 4; ++m)
#pragma unroll
        for (int n = 0; n < 4; ++n)
#pragma unroll
            for (int j = 0; j < 4; ++j) {
                int row = m0 + wm * 64 + m * 16 + g * 4 + j;
                int col = n0 + wn * 64 + n * 16 + r;
                if constexpr (OUT_BF16)
                    reinterpret_cast<unsigned short*>(Cm)[(size_t)row * ldc + col] = f2bf(acc[m][n][j]);
                else
                    reinterpret_cast<float*>(Cm)[(size_t)row * ldc + col] = acc[m][n][j];
            }
}

// ---------------- fused QKV GEMM: N=6144 (Q | K | V^T epilogue routing) ----------------
__global__ __launch_bounds__(256) void gemm_qkv(
    const unsigned short* __restrict__ A,      // xb [2048][4096]
    const unsigned short* __restrict__ BtQ,    // wqT [4096][4096]
    const unsigned short* __restrict__ BtKV,   // wkvT [2048][4096]
    unsigned short* __restrict__ Qb,           // [2048][4096]
    unsigned short* __restrict__ Kb,           // [2048][1024]
    unsigned short* __restrict__ VT,           // [2048][1024]
    int K)
{
    __shared__ unsigned short As[2][128 * 32];
    __shared__ unsigned short Bs[2][128 * 32];
    const int tid  = threadIdx.x;
    const int lane = tid & 63;
    const int w    = tid >> 6;
    const int wm   = w >> 1, wn = w & 1;
    const int r    = lane & 15, g = lane >> 4;

    const int nwg = gridDim.x * gridDim.y;
    const int D   = blockIdx.y * gridDim.x + blockIdx.x;
    const int L   = (D & 7) * (nwg >> 3) + (D >> 3);
    const int m0  = (L / gridDim.x) * 128, n0 = (L % gridDim.x) * 128;

    const unsigned short* Brow = (n0 < 4096) ? (BtQ + (size_t)n0 * K)
                                             : (BtKV + (size_t)(n0 - 4096) * K);

    const int c0 = w * 128 + lane;
    const int c1 = c0 + 64;
    const int r0 = c0 >> 2, col0 = (((c0 & 3) ^ (r0 & 3)) << 3);
    const int r1 = c1 >> 2, col1 = (((c1 & 3) ^ (r1 & 3)) << 3);
    const int sw = (g ^ (r & 3)) << 3;

    const f32x4_t zero = {0.f, 0.f, 0.f, 0.f};
    f32x4_t acc[4][4];
#pragma unroll
    for (int i = 0; i < 4; ++i)
#pragma unroll
        for (int j = 0; j < 4; ++j) acc[i][j] = zero;

    gload_lds16(&A   [(size_t)(m0 + r0) * K + col0], &As[0][(w * 2 + 0) * 512]);
    gload_lds16(&A   [(size_t)(m0 + r1) * K + col1], &As[0][(w * 2 + 1) * 512]);
    gload_lds16(&Brow[(size_t)r0 * K + col0],        &Bs[0][(w * 2 + 0) * 512]);
    gload_lds16(&Brow[(size_t)r1 * K + col1],        &Bs[0][(w * 2 + 1) * 512]);
    __syncthreads();

    int cur = 0;
    for (int k0 = 0; k0 < K; k0 += 32) {
        if (k0 + 32 < K) {
            const int nk = k0 + 32, nb = cur ^ 1;
            gload_lds16(&A   [(size_t)(m0 + r0) * K + nk + col0], &As[nb][(w * 2 + 0) * 512]);
            gload_lds16(&A   [(size_t)(m0 + r1) * K + nk + col1], &As[nb][(w * 2 + 1) * 512]);
            gload_lds16(&Brow[(size_t)r0 * K + nk + col0],        &Bs[nb][(w * 2 + 0) * 512]);
            gload_lds16(&Brow[(size_t)r1 * K + nk + col1],        &Bs[nb][(w * 2 + 1) * 512]);
        }
        bf16x8_t af[4], bfr[4];
#pragma unroll
        for (int m = 0; m < 4; ++m)
            af[m] = *reinterpret_cast<const bf16x8_t*>(&As[cur][(wm * 64 + m * 16 + r) * 32 + sw]);
#pragma unroll
        for (int n = 0; n < 4; ++n)
            bfr[n] = *reinterpret_cast<const bf16x8_t*>(&Bs[cur][(wn * 64 + n * 16 + r) * 32 + sw]);
#pragma unroll
        for (int m = 0; m < 4; ++m)
#pragma unroll
            for (int n = 0; n < 4; ++n)
                acc[m][n] = __builtin_amdgcn_mfma_f32_16x16x32_bf16(af[m], bfr[n], acc[m][n], 0, 0, 0);
        __syncthreads();
        cur ^= 1;
    }

#pragma unroll
    for (int m = 0; m < 4; ++m)
#pragma unroll
        for (int n = 0; n < 4; ++n) {
            int col  = n0 + wn * 64 + n * 16 + r;
            int row0 = m0 + wm * 64 + m * 16 + g * 4;
            if (n0 < 4096) {
#pragma unroll
                for (int j = 0; j < 4; ++j)
                    Qb[(size_t)(row0 + j) * 4096 + col] = f2bf(acc[m][n][j]);
            } else if (n0 < 5120) {
#pragma unroll
                for (int j = 0; j < 4; ++j)
                    Kb[(size_t)(row0 + j) * 1024 + (col - 4096)] = f2bf(acc[m][n][j]);
            } else {
                int d = col - 5120;
                int b = row0 >> 10, tokl = row0 & 1023;
                uint2 o;
                o.x = (unsigned)f2bf(acc[m][n][0]) | ((unsigned)f2bf(acc[m][n][1]) << 16);
                o.y = (unsigned)f2bf(acc[m][n][2]) | ((unsigned)f2bf(acc[m][n][3]) << 16);
                *reinterpret_cast<uint2*>(&VT[(size_t)(b * 1024 + d) * 1024 + tokl]) = o;
            }
        }
}

// ---------------- rope table: tab[tok][0:64]=cos, [64:128]=sin ----------------
__global__ __launch_bounds__(256) void rope_table_kernel(const int* __restrict__ start_pos,
                                                         float* __restrict__ tab) {
    int i = blockIdx.x * 256 + threadIdx.x;   // B*S*64
    int d = i & 63;
    int tok = i >> 6;
    int s = tok & (S_ - 1);
    int b = tok >> 10;
    float pos = (float)(start_pos[b] + s);
    float freq = __expf(-(float)d * (9.210340371976184f / 64.f));   // 10000^(-d/64)
    float ang = pos * freq;
    tab[tok * 128 + d]      = cosf(ang);
    tab[tok * 128 + 64 + d] = sinf(ang);
}

// ---------------- in-place NeoX rotary on bf16 [tok][*][128] ----------------
template<int LOGH, int STRIDE>
__global__ __launch_bounds__(256) void rope_apply_kernel(unsigned short* __restrict__ t,
                                                         const float* __restrict__ tab) {
    int i = blockIdx.x * 256 + threadIdx.x;   // B*S*Hn*64
    int d = i & 63;
    int h = (i >> 6) & ((1 << LOGH) - 1);
    int tok = i >> (6 + LOGH);
    size_t base = (size_t)tok * STRIDE + (size_t)h * 128;
    float c  = tab[tok * 128 + d];
    float sn = tab[tok * 128 + 64 + d];
    float a = bf2f(t[base + d]);
    float b = bf2f(t[base + 64 + d]);
    t[base + d]      = f2bf(a * c - b * sn);
    t[base + 64 + d] = f2bf(b * c + a * sn);
}

// ---------------- flash attention: 1 wave per (b, h, 32-row q tile) ----------------
__global__ __launch_bounds__(64) void attn_fwd(
    const unsigned short* __restrict__ Qb,   // [2048][4096]
    const unsigned short* __restrict__ Kb,   // [2048][1024]
    const unsigned short* __restrict__ VT,   // [2048][1024]  (b*1024+d rows, tok cols)
    unsigned short* __restrict__ Ob)         // [2048][4096]
{
    const int nQT = S_ / 32;
    const int qt = nQT - 1 - blockIdx.y;     // heavy-first
    const int h = blockIdx.x, b = blockIdx.z;
    const int kvh = h >> 2;
    const int lane = threadIdx.x;
    const int r = lane & 15, g = lane >> 4;
    __shared__ unsigned short P_lds[32][40];

    const int qrow0 = qt * 32;
    const unsigned short* Qp = Qb + ((size_t)(b * S_) + qrow0) * 4096 + h * 128;
    bf16x8_t qf[2][4];
#pragma unroll
    for (int q2 = 0; q2 < 2; ++q2)
#pragma unroll
        for (int kk = 0; kk < 4; ++kk)
            qf[q2][kk] = *reinterpret_cast<const bf16x8_t*>(
                &Qp[(size_t)(q2 * 16 + r) * 4096 + kk * 32 + g * 8]);

    const f32x4_t zero = {0.f, 0.f, 0.f, 0.f};
    f32x4_t o[2][8];
#pragma unroll
    for (int q2 = 0; q2 < 2; ++q2)
#pragma unroll
        for (int n = 0; n < 8; ++n) o[q2][n] = zero;
    float m_[2][4], s_[2][4];
#pragma unroll
    for (int q2 = 0; q2 < 2; ++q2)
#pragma unroll
        for (int j = 0; j < 4; ++j) { m_[q2][j] = -1e30f; s_[q2][j] = 0.f; }

    const float scale = 0.08838834764831845f;   // 1/sqrt(128)
    const unsigned short* Kp = Kb + (size_t)(b * S_) * 1024 + kvh * 128;
    const unsigned short* Vt = VT + ((size_t)(b * 1024) + kvh * 128) * 1024;
    const int ntiles = qt + 1;

    for (int t = 0; t < ntiles; ++t) {
        const int k0 = t << 5;
        // ---- QK^T: 32 kv cols (two 16-col halves), shared K frags ----
        f32x4_t sc[2][2];
        sc[0][0] = zero; sc[0][1] = zero; sc[1][0] = zero; sc[1][1] = zero;
        __builtin_amdgcn_s_setprio(1);
#pragma unroll
        for (int kk = 0; kk < 4; ++kk) {
            bf16x8_t kf0 = *reinterpret_cast<const bf16x8_t*>(
                &Kp[(size_t)(k0 + r) * 1024 + kk * 32 + g * 8]);
            bf16x8_t kf1 = *reinterpret_cast<const bf16x8_t*>(
                &Kp[(size_t)(k0 + 16 + r) * 1024 + kk * 32 + g * 8]);
#pragma unroll
            for (int q2 = 0; q2 < 2; ++q2) {
                sc[q2][0] = __builtin_amdgcn_mfma_f32_16x16x32_bf16(qf[q2][kk], kf0, sc[q2][0], 0, 0, 0);
                sc[q2][1] = __builtin_amdgcn_mfma_f32_16x16x32_bf16(qf[q2][kk], kf1, sc[q2][1], 0, 0, 0);
            }
        }
        __builtin_amdgcn_s_setprio(0);
        // ---- V^T B-fragments: contiguous 16B vector loads (issued before softmax) ----
        bf16x8_t vf[8];
#pragma unroll
        for (int n = 0; n < 8; ++n)
            vf[n] = *reinterpret_cast<const bf16x8_t*>(
                &Vt[(size_t)(n * 16 + r) * 1024 + k0 + g * 8]);
        // ---- online softmax (row q2*16+g*4+j; cols r, 16+r) ----
        float al[2][4];
#pragma unroll
        for (int q2 = 0; q2 < 2; ++q2)
#pragma unroll
            for (int j = 0; j < 4; ++j) {
                int row = qrow0 + q2 * 16 + g * 4 + j;
                float v0 = sc[q2][0][j] * scale + ((k0 + r)      > row ? -1e9f : 0.f);
                float v1 = sc[q2][1][j] * scale + ((k0 + 16 + r) > row ? -1e9f : 0.f);
                float mx = fmaxf(v0, v1);
#pragma unroll
                for (int off = 1; off < 16; off <<= 1)
                    mx = fmaxf(mx, __shfl_xor(mx, off));
                float mn = fmaxf(m_[q2][j], mx);
                al[q2][j] = __expf(m_[q2][j] - mn);
                float p0 = __expf(v0 - mn);
                float p1 = __expf(v1 - mn);
                float rs = p0 + p1;
#pragma unroll
                for (int off = 1; off < 16; off <<= 1)
                    rs += __shfl_xor(rs, off);
                s_[q2][j] = s_[q2][j] * al[q2][j] + rs;
                m_[q2][j] = mn;
                P_lds[q2 * 16 + g * 4 + j][r]      = f2bf(p0);
                P_lds[q2 * 16 + g * 4 + j][16 + r] = f2bf(p1);
            }
#pragma unroll
        for (int q2 = 0; q2 < 2; ++q2)
#pragma unroll
            for (int n = 0; n < 8; ++n)
#pragma unroll
                for (int j = 0; j < 4; ++j)
                    o[q2][n][j] *= al[q2][j];
        __syncthreads();
        bf16x8_t pa[2];
        pa[0] = *reinterpret_cast<const bf16x8_t*>(&P_lds[r][g * 8]);
        pa[1] = *reinterpret_cast<const bf16x8_t*>(&P_lds[16 + r][g * 8]);
        // ---- PV: O += P @ V with vector-loaded V^T fragments ----
        __builtin_amdgcn_s_setprio(1);
#pragma unroll
        for (int n = 0; n < 8; ++n)
#pragma unroll
            for (int q2 = 0; q2 < 2; ++q2)
                o[q2][n] = __builtin_amdgcn_mfma_f32_16x16x32_bf16(pa[q2], vf[n], o[q2][n], 0, 0, 0);
        __builtin_amdgcn_s_setprio(0);
        __syncthreads();
    }
    // ---- epilogue ----
    unsigned short* Op = Ob + ((size_t)(b * S_) + qrow0) * 4096 + h * 128;
#pragma unroll
    for (int q2 = 0; q2 < 2; ++q2)
#pragma unroll
        for (int n = 0; n < 8; ++n)
#pragma unroll
            for (int j = 0; j < 4; ++j) {
                float val = o[q2][n][j] / s_[q2][j];
                Op[(size_t)(q2 * 16 + g * 4 + j) * 4096 + n * 16 + r] = f2bf(val);
            }
}

// ---------------- launcher ----------------
extern "C" void kernel_launch(void* const* d_in, const int* in_sizes, int n_in,
                              void* d_out, int out_size, void* d_ws, size_t ws_size,
                              hipStream_t stream)
{
    const float* x  = (const float*)d_in[0];
    const float* wq = (const float*)d_in[2];
    const float* wk = (const float*)d_in[3];
    const float* wv = (const float*)d_in[4];
    const float* wo = (const float*)d_in[5];
    const int* start_pos = (const int*)d_in[10];

    char* ws = (char*)d_ws;
    unsigned short* xb   = (unsigned short*)(ws);                   // [0,16M)  x bf16, later attn out
    unsigned short* qb   = (unsigned short*)(ws + (16u << 20));     // [16,32M) Q
    unsigned short* kb   = (unsigned short*)(ws + (32u << 20));     // [32,36M) K
    unsigned short* vT   = (unsigned short*)(ws + (36u << 20));     // [36,40M) V^T
    unsigned short* wkvT = (unsigned short*)(ws + (40u << 20));     // [40,56M) wk^T|wv^T
    float*          tb   = (float*)(ws + (56u << 20));              // [56,57M) rope table
    unsigned short* ab   = xb;                                      // attn out reuses xb
    unsigned short* wqT  = (unsigned short*)d_out;                  // 32 MB scratch until final store
    unsigned short* woT  = qb;                                      // [16,48M): 32 MB, free after attn

    // 1) x -> bf16
    cvt_f32_bf16<<<8192, 256, 0, stream>>>(x, xb, (B_ * S_ * HID_) / 4);

    // 2) weight transposes (wq^T in d_out; wk^T|wv^T in ws)
    tcvt<<<dim3(128, 128), 256, 0, stream>>>(wq, wqT, HID_, HID_);
    tcvt<<<dim3(32, 128), 256, 0, stream>>>(wk, wkvT, 1024, HID_);
    tcvt<<<dim3(32, 128), 256, 0, stream>>>(wv, wkvT + (size_t)1024 * HID_, 1024, HID_);

    // 3) fused QKV projection (N=6144), V written transposed
    gemm_qkv<<<dim3(48, 16), 256, 0, stream>>>(xb, wqT, wkvT, qb, kb, vT, HID_);

    // 4) rotary (V untouched)
    rope_table_kernel<<<512, 256, 0, stream>>>(start_pos, tb);
    rope_apply_kernel<5, 4096><<<16384, 256, 0, stream>>>(qb, tb);
    rope_apply_kernel<3, 1024><<<4096, 256, 0, stream>>>(kb, tb);

    // 5) causal GQA flash attention
    attn_fwd<<<dim3(H_, S_ / 32, B_), 64, 0, stream>>>(qb, kb, vT, ab);

    // 6) output projection (wo^T staged over qb region) -> fp32 d_out
    tcvt<<<dim3(128, 128), 256, 0, stream>>>(wo, woT, HID_, HID_);
    gemm_tt<false><<<dim3(32, 16), 256, 0, stream>>>(ab, woT, (float*)d_out, 4096, HID_);
}